// Round 1
// baseline (292.304 us; speedup 1.0000x reference)
//
#include <hip/hip_runtime.h>
#include <hip/hip_bf16.h>
#include <stdint.h>

typedef unsigned short ushort_t;
typedef __attribute__((ext_vector_type(4))) float f32x4;
typedef __attribute__((ext_vector_type(8))) __bf16 bf16x8;
typedef __attribute__((ext_vector_type(8))) unsigned short ushort8;
typedef __attribute__((ext_vector_type(4))) unsigned short ushort4v;

__device__ __forceinline__ float bf2f(ushort_t u) {
  union { unsigned u32; float f; } x; x.u32 = ((unsigned)u) << 16; return x.f;
}
__device__ __forceinline__ ushort_t f2bf(float f) {
  union { float f; unsigned u; } x; x.f = f;
  unsigned r = x.u + 0x7FFF + ((x.u >> 16) & 1);
  return (ushort_t)(r >> 16);
}

// ---------------- cast fp32 -> bf16, 8 elems/thread ----------------
__global__ __launch_bounds__(256) void cast_bf16_kernel(
    const float* __restrict__ in, ushort_t* __restrict__ out, int n8) {
  int i = blockIdx.x * 256 + threadIdx.x;
  if (i >= n8) return;
  const f32x4* p = (const f32x4*)in;
  f32x4 a = p[2 * i];
  f32x4 b = p[2 * i + 1];
  ushort8 o;
  o[0] = f2bf(a[0]); o[1] = f2bf(a[1]); o[2] = f2bf(a[2]); o[3] = f2bf(a[3]);
  o[4] = f2bf(b[0]); o[5] = f2bf(b[1]); o[6] = f2bf(b[2]); o[7] = f2bf(b[3]);
  *((ushort8*)out + i) = o;
}

// ---------------- GEMM: C = A * B^T  (A[M,K], B[N,K], both bf16 row-major) --
#define BM 128
#define BN 128
#define BK 32

enum { OUT_BF16 = 0, OUT_BF16T = 1, OUT_F32 = 2 };

template <int OUT, bool CAUSAL_SKIP, bool K_LIMIT>
__global__ __launch_bounds__(256, 3) void gemm_bt(
    const ushort_t* __restrict__ Ag, const ushort_t* __restrict__ Bg,
    void* __restrict__ Cg, int M, int N, int Kd,
    long sA, long sB, long sC, float scale) {
  int m0 = blockIdx.y * BM, n0 = blockIdx.x * BN;
  if (CAUSAL_SKIP && n0 > m0 + (BM - 1)) return;  // fully-masked upper tile
  int bz = blockIdx.z;
  const ushort_t* A = Ag + (size_t)bz * sA;
  const ushort_t* B = Bg + (size_t)bz * sB;

  int kEnd = K_LIMIT ? min(Kd, m0 + BM) : Kd;  // causal: P cols > row are 0

  __shared__ ushort_t As[BM * BK];
  __shared__ ushort_t Bs[BN * BK];

  int tid = threadIdx.x;
  int lane = tid & 63;
  int wave = tid >> 6;
  int wr = (wave >> 1) * 64;  // wave row base in tile
  int wc = (wave & 1) * 64;   // wave col base in tile
  int ln15 = lane & 15;
  int kq = lane >> 4;

  f32x4 acc[4][4];
#pragma unroll
  for (int i = 0; i < 4; ++i)
#pragma unroll
    for (int j = 0; j < 4; ++j) acc[i][j] = f32x4{0.f, 0.f, 0.f, 0.f};

  // staging chunk map: chunk c (0..511) covers tile row c>>2, k-offset (c&3)*8
  int c0 = tid, c1 = 256 + tid;
  const ushort_t* a0p = A + (size_t)(m0 + (c0 >> 2)) * Kd + (c0 & 3) * 8;
  const ushort_t* a1p = A + (size_t)(m0 + (c1 >> 2)) * Kd + (c1 & 3) * 8;
  const ushort_t* b0p = B + (size_t)(n0 + (c0 >> 2)) * Kd + (c0 & 3) * 8;
  const ushort_t* b1p = B + (size_t)(n0 + (c1 >> 2)) * Kd + (c1 & 3) * 8;

  for (int k0 = 0; k0 < kEnd; k0 += BK) {
    ushort8 ra0 = *(const ushort8*)(a0p + k0);
    ushort8 ra1 = *(const ushort8*)(a1p + k0);
    ushort8 rb0 = *(const ushort8*)(b0p + k0);
    ushort8 rb1 = *(const ushort8*)(b1p + k0);
    __syncthreads();
    *(ushort8*)&As[c0 * 8] = ra0;
    *(ushort8*)&As[c1 * 8] = ra1;
    *(ushort8*)&Bs[c0 * 8] = rb0;
    *(ushort8*)&Bs[c1 * 8] = rb1;
    __syncthreads();
    bf16x8 af[4], bfr[4];
#pragma unroll
    for (int i = 0; i < 4; ++i)
      af[i] = *(const bf16x8*)&As[(wr + i * 16 + ln15) * BK + kq * 8];
#pragma unroll
    for (int j = 0; j < 4; ++j)
      bfr[j] = *(const bf16x8*)&Bs[(wc + j * 16 + ln15) * BK + kq * 8];
#pragma unroll
    for (int i = 0; i < 4; ++i)
#pragma unroll
      for (int j = 0; j < 4; ++j)
        acc[i][j] =
            __builtin_amdgcn_mfma_f32_16x16x32_bf16(af[i], bfr[j], acc[i][j], 0, 0, 0);
  }

  // C/D layout (verified m89): col = lane&15, row = (lane>>4)*4 + reg
  if (OUT == OUT_BF16) {
    ushort_t* C = (ushort_t*)Cg + (size_t)bz * sC;
#pragma unroll
    for (int i = 0; i < 4; ++i) {
      int row0 = m0 + wr + i * 16 + kq * 4;
#pragma unroll
      for (int j = 0; j < 4; ++j) {
        int col = n0 + wc + j * 16 + ln15;
#pragma unroll
        for (int r = 0; r < 4; ++r)
          C[(size_t)(row0 + r) * N + col] = f2bf(acc[i][j][r] * scale);
      }
    }
  } else if (OUT == OUT_BF16T) {
    // V transposed: Vt[b][d][n], b = token>>11, n = token&2047 (4x2048x1024)
    ushort_t* C = (ushort_t*)Cg;
#pragma unroll
    for (int i = 0; i < 4; ++i) {
      int gm = m0 + wr + i * 16 + kq * 4;  // token index
      int b = gm >> 11, nn = gm & 2047;
#pragma unroll
      for (int j = 0; j < 4; ++j) {
        int d = n0 + wc + j * 16 + ln15;
        ushort4v v;
#pragma unroll
        for (int r = 0; r < 4; ++r) v[r] = f2bf(acc[i][j][r]);
        *(ushort4v*)&C[(size_t)b * (2048 * 1024) + (size_t)d * 2048 + nn] = v;
      }
    }
  } else {
    float* C = (float*)Cg + (size_t)bz * sC;
#pragma unroll
    for (int i = 0; i < 4; ++i) {
      int row0 = m0 + wr + i * 16 + kq * 4;
#pragma unroll
      for (int j = 0; j < 4; ++j) {
        int col = n0 + wc + j * 16 + ln15;
#pragma unroll
        for (int r = 0; r < 4; ++r)
          C[(size_t)(row0 + r) * N + col] = acc[i][j][r] * scale;
      }
    }
  }
}

// ---------------- causal softmax over rows of S (bf16 in, bf16 out) --------
__global__ __launch_bounds__(256) void softmax_causal(
    const ushort_t* __restrict__ S, ushort_t* __restrict__ P) {
  int row = blockIdx.x;   // 0..8191 (batch*2048 + i)
  int i = row & 2047;
  const ushort8* s = (const ushort8*)(S + (size_t)row * 2048);
  ushort8* p = (ushort8*)(P + (size_t)row * 2048);
  int t = threadIdx.x;
  ushort8 raw = s[t];
  int c0 = t * 8;
  float v[8];
  float m = -INFINITY;
#pragma unroll
  for (int j = 0; j < 8; ++j) {
    float f = bf2f(raw[j]);
    v[j] = (c0 + j <= i) ? f : -INFINITY;  // mask by index (upper tiles unwritten)
    m = fmaxf(m, v[j]);
  }
#pragma unroll
  for (int off = 32; off > 0; off >>= 1) m = fmaxf(m, __shfl_xor(m, off));
  __shared__ float redm[4], reds[4];
  int lane = t & 63, wave = t >> 6;
  if (lane == 0) redm[wave] = m;
  __syncthreads();
  m = fmaxf(fmaxf(redm[0], redm[1]), fmaxf(redm[2], redm[3]));
  float e[8];
  float sum = 0.f;
#pragma unroll
  for (int j = 0; j < 8; ++j) {
    e[j] = __expf(v[j] - m);  // -inf -> 0
    sum += e[j];
  }
#pragma unroll
  for (int off = 32; off > 0; off >>= 1) sum += __shfl_xor(sum, off);
  if (lane == 0) reds[wave] = sum;
  __syncthreads();
  sum = reds[0] + reds[1] + reds[2] + reds[3];
  float inv = 1.0f / sum;
  ushort8 o;
#pragma unroll
  for (int j = 0; j < 8; ++j) o[j] = f2bf(e[j] * inv);
  p[t] = o;
}

// ---------------- launch ----------------
extern "C" void kernel_launch(void* const* d_in, const int* in_sizes, int n_in,
                              void* d_out, int out_size, void* d_ws, size_t ws_size,
                              hipStream_t stream) {
  const float* x = (const float*)d_in[0];
  const float* Wq = (const float*)d_in[1];
  const float* Wk = (const float*)d_in[2];
  const float* Wv = (const float*)d_in[3];
  float* out = (float*)d_out;
  char* ws = (char*)d_ws;

  // workspace layout (bytes)
  ushort_t* xb = (ushort_t*)(ws);                       // 16 MB  x bf16
  ushort_t* wqb = (ushort_t*)(ws + (16ull << 20));      // 2 MB
  ushort_t* wkb = (ushort_t*)(ws + (18ull << 20));      // 2 MB
  ushort_t* wvb = (ushort_t*)(ws + (20ull << 20));      // 2 MB
  ushort_t* Qb = (ushort_t*)(ws + (22ull << 20));       // 16 MB
  ushort_t* Kb = (ushort_t*)(ws + (38ull << 20));       // 16 MB
  ushort_t* Vt = (ushort_t*)(ws + (54ull << 20));       // 16 MB (transposed)
  ushort_t* Sb = (ushort_t*)(ws + (70ull << 20));       // 32 MB scores bf16
  ushort_t* Pb = (ushort_t*)(ws + (102ull << 20));      // 32 MB probs bf16

  cast_bf16_kernel<<<4096, 256, 0, stream>>>(x, xb, 8388608 / 8);
  cast_bf16_kernel<<<512, 256, 0, stream>>>(Wq, wqb, 1048576 / 8);
  cast_bf16_kernel<<<512, 256, 0, stream>>>(Wk, wkb, 1048576 / 8);
  cast_bf16_kernel<<<512, 256, 0, stream>>>(Wv, wvb, 1048576 / 8);

  dim3 gQKV(1024 / BN, 8192 / BM, 1);  // (8, 64)
  gemm_bt<OUT_BF16, false, false><<<gQKV, 256, 0, stream>>>(
      xb, wqb, Qb, 8192, 1024, 1024, 0, 0, 0, 1.0f);
  gemm_bt<OUT_BF16, false, false><<<gQKV, 256, 0, stream>>>(
      xb, wkb, Kb, 8192, 1024, 1024, 0, 0, 0, 1.0f);
  gemm_bt<OUT_BF16T, false, false><<<gQKV, 256, 0, stream>>>(
      xb, wvb, Vt, 8192, 1024, 1024, 0, 0, 0, 1.0f);

  dim3 gS(2048 / BN, 2048 / BM, 4);  // (16, 16, 4)
  gemm_bt<OUT_BF16, true, false><<<gS, 256, 0, stream>>>(
      Qb, Kb, Sb, 2048, 2048, 1024, 2048 * 1024, 2048 * 1024, 2048 * 2048,
      0.03125f);  // 1/sqrt(1024)

  softmax_causal<<<8192, 256, 0, stream>>>(Sb, Pb);

  dim3 gO(1024 / BN, 2048 / BM, 4);  // (8, 16, 4)
  gemm_bt<OUT_F32, false, true><<<gO, 256, 0, stream>>>(
      Pb, Vt, out, 2048, 1024, 2048, 2048 * 2048, 1024 * 2048, 2048 * 1024, 1.0f);
}

// Round 2
// 274.236 us; speedup vs baseline: 1.0659x; 1.0659x over previous
//
#include <hip/hip_runtime.h>
#include <hip/hip_bf16.h>
#include <stdint.h>

typedef unsigned short ushort_t;
typedef __attribute__((ext_vector_type(4))) float f32x4;
typedef __attribute__((ext_vector_type(8))) __bf16 bf16x8;
typedef __attribute__((ext_vector_type(8))) unsigned short ushort8;
typedef __attribute__((ext_vector_type(4))) unsigned short ushort4v;

__device__ __forceinline__ float bf2f(ushort_t u) {
  union { unsigned u32; float f; } x; x.u32 = ((unsigned)u) << 16; return x.f;
}
__device__ __forceinline__ ushort_t f2bf(float f) {
  union { float f; unsigned u; } x; x.f = f;
  unsigned r = x.u + 0x7FFF + ((x.u >> 16) & 1);
  return (ushort_t)(r >> 16);
}

// async global->LDS, 16 bytes per lane (global_load_lds_dwordx4)
__device__ __forceinline__ void gld16(const ushort_t* g, ushort_t* l) {
  __builtin_amdgcn_global_load_lds(
      (const __attribute__((address_space(1))) uint32_t*)g,
      (__attribute__((address_space(3))) uint32_t*)l, 16, 0, 0);
}

// ---------------- cast fp32 -> bf16, 8 elems/thread ----------------
__global__ __launch_bounds__(256) void cast_bf16_kernel(
    const float* __restrict__ in, ushort_t* __restrict__ out, int n8) {
  int i = blockIdx.x * 256 + threadIdx.x;
  if (i >= n8) return;
  const f32x4* p = (const f32x4*)in;
  f32x4 a = p[2 * i];
  f32x4 b = p[2 * i + 1];
  ushort8 o;
  o[0] = f2bf(a[0]); o[1] = f2bf(a[1]); o[2] = f2bf(a[2]); o[3] = f2bf(a[3]);
  o[4] = f2bf(b[0]); o[5] = f2bf(b[1]); o[6] = f2bf(b[2]); o[7] = f2bf(b[3]);
  *((ushort8*)out + i) = o;
}

// ---------------- GEMM tile core: C = A * B^T ----------------
#define BM 128
#define BN 128
#define BK 32

enum { OUT_BF16 = 0, OUT_BF16T = 1, OUT_F32 = 2 };

// shared inner loop: stage via global_load_lds, ds_read fragments, MFMA
__device__ __forceinline__ void gemm_core(
    const ushort_t* __restrict__ A, const ushort_t* __restrict__ B, int Kd,
    int kEnd, int m0, int n0, ushort_t* As, ushort_t* Bs, f32x4 (&acc)[4][4]) {
  int tid = threadIdx.x;
  int lane = tid & 63;
  int wave = tid >> 6;
  int wr = (wave >> 1) * 64;
  int wc = (wave & 1) * 64;
  int ln15 = lane & 15;
  int kq = lane >> 4;

  // staging chunk map: chunk c (0..511) covers tile row c>>2, k-offset (c&3)*8
  int c0 = tid, c1 = 256 + tid;
  const ushort_t* a0p = A + (size_t)(m0 + (c0 >> 2)) * Kd + (c0 & 3) * 8;
  const ushort_t* a1p = A + (size_t)(m0 + (c1 >> 2)) * Kd + (c1 & 3) * 8;
  const ushort_t* b0p = B + (size_t)(n0 + (c0 >> 2)) * Kd + (c0 & 3) * 8;
  const ushort_t* b1p = B + (size_t)(n0 + (c1 >> 2)) * Kd + (c1 & 3) * 8;

  for (int k0 = 0; k0 < kEnd; k0 += BK) {
    __syncthreads();  // previous tile fully consumed
    gld16(a0p + k0, &As[c0 * 8]);
    gld16(a1p + k0, &As[c1 * 8]);
    gld16(b0p + k0, &Bs[c0 * 8]);
    gld16(b1p + k0, &Bs[c1 * 8]);
    __syncthreads();  // vmcnt(0) drain before reads
    bf16x8 af[4], bfr[4];
#pragma unroll
    for (int i = 0; i < 4; ++i)
      af[i] = *(const bf16x8*)&As[(wr + i * 16 + ln15) * BK + kq * 8];
#pragma unroll
    for (int j = 0; j < 4; ++j)
      bfr[j] = *(const bf16x8*)&Bs[(wc + j * 16 + ln15) * BK + kq * 8];
#pragma unroll
    for (int i = 0; i < 4; ++i)
#pragma unroll
      for (int j = 0; j < 4; ++j)
        acc[i][j] = __builtin_amdgcn_mfma_f32_16x16x32_bf16(af[i], bfr[j],
                                                            acc[i][j], 0, 0, 0);
  }
}

template <int OUT, bool CAUSAL_SKIP, bool K_LIMIT>
__global__ __launch_bounds__(256, 4) void gemm_bt(
    const ushort_t* __restrict__ Ag, const ushort_t* __restrict__ Bg,
    void* __restrict__ Cg, int M, int N, int Kd,
    long sA, long sB, long sC, float scale) {
  int m0 = blockIdx.y * BM, n0 = blockIdx.x * BN;
  if (CAUSAL_SKIP && n0 > m0 + (BM - 1)) return;
  int bz = blockIdx.z;
  const ushort_t* A = Ag + (size_t)bz * sA;
  const ushort_t* B = Bg + (size_t)bz * sB;
  int kEnd = K_LIMIT ? min(Kd, m0 + BM) : Kd;

  __shared__ ushort_t As[BM * BK];
  __shared__ ushort_t Bs[BN * BK];

  f32x4 acc[4][4];
#pragma unroll
  for (int i = 0; i < 4; ++i)
#pragma unroll
    for (int j = 0; j < 4; ++j) acc[i][j] = f32x4{0.f, 0.f, 0.f, 0.f};

  gemm_core(A, B, Kd, kEnd, m0, n0, As, Bs, acc);

  int tid = threadIdx.x;
  int lane = tid & 63;
  int wave = tid >> 6;
  int wr = (wave >> 1) * 64;
  int wc = (wave & 1) * 64;
  int ln15 = lane & 15;
  int kq = lane >> 4;

  // C/D layout (verified m89): col = lane&15, row = (lane>>4)*4 + reg
  if (OUT == OUT_BF16) {
    ushort_t* C = (ushort_t*)Cg + (size_t)bz * sC;
#pragma unroll
    for (int i = 0; i < 4; ++i) {
      int row0 = m0 + wr + i * 16 + kq * 4;
#pragma unroll
      for (int j = 0; j < 4; ++j) {
        int col = n0 + wc + j * 16 + ln15;
#pragma unroll
        for (int r = 0; r < 4; ++r)
          C[(size_t)(row0 + r) * N + col] = f2bf(acc[i][j][r] * scale);
      }
    }
  } else {
    float* C = (float*)Cg + (size_t)bz * sC;
#pragma unroll
    for (int i = 0; i < 4; ++i) {
      int row0 = m0 + wr + i * 16 + kq * 4;
#pragma unroll
      for (int j = 0; j < 4; ++j) {
        int col = n0 + wc + j * 16 + ln15;
#pragma unroll
        for (int r = 0; r < 4; ++r)
          C[(size_t)(row0 + r) * N + col] = acc[i][j][r] * scale;
      }
    }
  }
}

// merged QKV projection: z=0 -> Q, z=1 -> K, z=2 -> V (transposed per batch)
__global__ __launch_bounds__(256, 4) void gemm_qkv(
    const ushort_t* __restrict__ xb, const ushort_t* __restrict__ wq,
    const ushort_t* __restrict__ wk, const ushort_t* __restrict__ wv,
    ushort_t* __restrict__ Qb, ushort_t* __restrict__ Kb,
    ushort_t* __restrict__ Vt) {
  int m0 = blockIdx.y * BM, n0 = blockIdx.x * BN;
  int z = blockIdx.z;
  const ushort_t* B = (z == 0) ? wq : (z == 1) ? wk : wv;

  __shared__ ushort_t As[BM * BK];
  __shared__ ushort_t Bs[BN * BK];

  f32x4 acc[4][4];
#pragma unroll
  for (int i = 0; i < 4; ++i)
#pragma unroll
    for (int j = 0; j < 4; ++j) acc[i][j] = f32x4{0.f, 0.f, 0.f, 0.f};

  gemm_core(xb, B, 1024, 1024, m0, n0, As, Bs, acc);

  int tid = threadIdx.x;
  int lane = tid & 63;
  int wave = tid >> 6;
  int wr = (wave >> 1) * 64;
  int wc = (wave & 1) * 64;
  int ln15 = lane & 15;
  int kq = lane >> 4;

  if (z < 2) {
    ushort_t* C = (z == 0) ? Qb : Kb;
#pragma unroll
    for (int i = 0; i < 4; ++i) {
      int row0 = m0 + wr + i * 16 + kq * 4;
#pragma unroll
      for (int j = 0; j < 4; ++j) {
        int col = n0 + wc + j * 16 + ln15;
#pragma unroll
        for (int r = 0; r < 4; ++r)
          C[(size_t)(row0 + r) * 1024 + col] = f2bf(acc[i][j][r]);
      }
    }
  } else {
    // V transposed: Vt[b][d][n], token gm -> b = gm>>11, n = gm&2047
#pragma unroll
    for (int i = 0; i < 4; ++i) {
      int gm = m0 + wr + i * 16 + kq * 4;
      int b = gm >> 11, nn = gm & 2047;
#pragma unroll
      for (int j = 0; j < 4; ++j) {
        int d = n0 + wc + j * 16 + ln15;
        ushort4v v;
#pragma unroll
        for (int r = 0; r < 4; ++r) v[r] = f2bf(acc[i][j][r]);
        *(ushort4v*)&Vt[(size_t)b * (2048 * 1024) + (size_t)d * 2048 + nn] = v;
      }
    }
  }
}

// ---------------- causal softmax over rows of S (bf16 in, bf16 out) --------
__global__ __launch_bounds__(256) void softmax_causal(
    const ushort_t* __restrict__ S, ushort_t* __restrict__ P) {
  int row = blockIdx.x;  // 0..8191 (batch*2048 + i)
  int i = row & 2047;
  const ushort8* s = (const ushort8*)(S + (size_t)row * 2048);
  ushort8* p = (ushort8*)(P + (size_t)row * 2048);
  int t = threadIdx.x;
  ushort8 raw = s[t];
  int c0 = t * 8;
  float v[8];
  float m = -INFINITY;
#pragma unroll
  for (int j = 0; j < 8; ++j) {
    float f = bf2f(raw[j]);
    v[j] = (c0 + j <= i) ? f : -INFINITY;
    m = fmaxf(m, v[j]);
  }
#pragma unroll
  for (int off = 32; off > 0; off >>= 1) m = fmaxf(m, __shfl_xor(m, off));
  __shared__ float redm[4], reds[4];
  int lane = t & 63, wave = t >> 6;
  if (lane == 0) redm[wave] = m;
  __syncthreads();
  m = fmaxf(fmaxf(redm[0], redm[1]), fmaxf(redm[2], redm[3]));
  float e[8];
  float sum = 0.f;
#pragma unroll
  for (int j = 0; j < 8; ++j) {
    e[j] = __expf(v[j] - m);
    sum += e[j];
  }
#pragma unroll
  for (int off = 32; off > 0; off >>= 1) sum += __shfl_xor(sum, off);
  if (lane == 0) reds[wave] = sum;
  __syncthreads();
  sum = reds[0] + reds[1] + reds[2] + reds[3];
  float inv = 1.0f / sum;
  ushort8 o;
#pragma unroll
  for (int j = 0; j < 8; ++j) o[j] = f2bf(e[j] * inv);
  p[t] = o;
}

// ---------------- launch ----------------
extern "C" void kernel_launch(void* const* d_in, const int* in_sizes, int n_in,
                              void* d_out, int out_size, void* d_ws, size_t ws_size,
                              hipStream_t stream) {
  const float* x = (const float*)d_in[0];
  const float* Wq = (const float*)d_in[1];
  const float* Wk = (const float*)d_in[2];
  const float* Wv = (const float*)d_in[3];
  float* out = (float*)d_out;
  char* ws = (char*)d_ws;

  ushort_t* xb = (ushort_t*)(ws);                   // 16 MB
  ushort_t* wqb = (ushort_t*)(ws + (16ull << 20));  // 2 MB
  ushort_t* wkb = (ushort_t*)(ws + (18ull << 20));  // 2 MB
  ushort_t* wvb = (ushort_t*)(ws + (20ull << 20));  // 2 MB
  ushort_t* Qb = (ushort_t*)(ws + (22ull << 20));   // 16 MB
  ushort_t* Kb = (ushort_t*)(ws + (38ull << 20));   // 16 MB
  ushort_t* Vt = (ushort_t*)(ws + (54ull << 20));   // 16 MB (transposed)
  ushort_t* Sb = (ushort_t*)(ws + (70ull << 20));   // 32 MB
  ushort_t* Pb = (ushort_t*)(ws + (102ull << 20));  // 32 MB

  cast_bf16_kernel<<<4096, 256, 0, stream>>>(x, xb, 8388608 / 8);
  cast_bf16_kernel<<<512, 256, 0, stream>>>(Wq, wqb, 1048576 / 8);
  cast_bf16_kernel<<<512, 256, 0, stream>>>(Wk, wkb, 1048576 / 8);
  cast_bf16_kernel<<<512, 256, 0, stream>>>(Wv, wvb, 1048576 / 8);

  dim3 gQKV(1024 / BN, 8192 / BM, 3);  // (8, 64, 3) merged Q/K/V
  gemm_qkv<<<gQKV, 256, 0, stream>>>(xb, wqb, wkb, wvb, Qb, Kb, Vt);

  dim3 gS(2048 / BN, 2048 / BM, 4);  // (16, 16, 4)
  gemm_bt<OUT_BF16, true, false><<<gS, 256, 0, stream>>>(
      Qb, Kb, Sb, 2048, 2048, 1024, 2048 * 1024, 2048 * 1024, 2048 * 2048,
      0.03125f);

  softmax_causal<<<8192, 256, 0, stream>>>(Sb, Pb);

  dim3 gO(1024 / BN, 2048 / BM, 4);  // (8, 16, 4)
  gemm_bt<OUT_F32, false, true><<<gO, 256, 0, stream>>>(
      Pb, Vt, out, 2048, 1024, 2048, 2048 * 2048, 1024 * 2048, 2048 * 1024,
      1.0f);
}